// Round 6
// baseline (1909.773 us; speedup 1.0000x reference)
//
#include <hip/hip_runtime.h>
#include <stdint.h>

typedef __attribute__((ext_vector_type(8))) short short8;
typedef __attribute__((ext_vector_type(4))) float f32x4;
typedef __attribute__((ext_vector_type(4))) unsigned int u32x4;
typedef unsigned short u16;
typedef unsigned int u32;

#define NPER 6
#define NPANEL 50
#define PANEL_B 16384
#define WS_WELE (NPANEL * 8192)      // 409600 bf16 elements of panel weights; h16 follows

__device__ inline u16 f2b(float f){                 // f32 -> bf16 (RNE)
  u32 u = __builtin_bit_cast(u32, f);
  u = u + 0x7FFFu + ((u >> 16) & 1u);
  return (u16)(u >> 16);
}
__device__ inline float b2f(u16 v){ return __builtin_bit_cast(float, ((u32)v) << 16); }
__device__ inline float elu1(float x){ return x > 0.f ? x : (__expf(x) - 1.f); }
__device__ inline u32 packbf(float a, float b){ return (u32)f2b(a) | ((u32)f2b(b) << 16); }

// ---- weight panels, in exact phase order ----
// p 0..7   : sw  k 0..255   (g = p)          p 8..15  : sw  k 256..511 (g = p-8)
// p 16..23 : c_rw           p 24..31 : c_w1   p 32     : c_w2 (rows 6..31 zero)
// p 33..40 : t_rw           p 41..48 : t_w1   p 49     : t_w2 (rows 6..31 zero)
// panel layout: [32 n][256 k] row-major bf16, contiguous 16384 B
__global__ __launch_bounds__(256) void convert_weights(
    const float* __restrict__ sw, const float* __restrict__ crw, const float* __restrict__ cw1,
    const float* __restrict__ cw2, const float* __restrict__ trw, const float* __restrict__ tw1,
    const float* __restrict__ tw2, u16* __restrict__ ws){
  int i = blockIdx.x * 256 + threadIdx.x;
  if (i >= WS_WELE) return;
  int p = i >> 13;
  int e = i & 8191;
  int n = e >> 8, k = e & 255;
  float v;
  if (p < 8)        v = sw[(p * 32 + n) * 512 + k];
  else if (p < 16)  v = sw[((p - 8) * 32 + n) * 512 + 256 + k];
  else if (p < 24)  v = crw[((p - 16) * 32 + n) * 256 + k];
  else if (p < 32)  v = cw1[((p - 24) * 32 + n) * 256 + k];
  else if (p == 32) v = (n < NPER) ? cw2[n * 256 + k] : 0.f;
  else if (p < 41)  v = trw[((p - 33) * 32 + n) * 256 + k];
  else if (p < 49)  v = tw1[((p - 41) * 32 + n) * 256 + k];
  else              v = (n < NPER) ? tw2[n * 256 + k] : 0.f;
  ws[i] = f2b(v);
}

__global__ __launch_bounds__(256) void convert_h(
    const float* __restrict__ h, u16* __restrict__ h16, int n8){
  int i = blockIdx.x * 256 + threadIdx.x;
  if (i >= n8) return;
  const float4* src = (const float4*)(h + (size_t)i * 8);
  float4 q0 = src[0], q1 = src[1];
  short8 v;
  v[0]=(short)f2b(q0.x); v[1]=(short)f2b(q0.y); v[2]=(short)f2b(q0.z); v[3]=(short)f2b(q0.w);
  v[4]=(short)f2b(q1.x); v[5]=(short)f2b(q1.y); v[6]=(short)f2b(q1.z); v[7]=(short)f2b(q1.w);
  *(short8*)(h16 + (size_t)i * 8) = v;
}

template<bool H16>
__global__ __launch_bounds__(256) void torsion_kernel(
    const float* __restrict__ h, const u16* __restrict__ h16,
    const int* __restrict__ idxs, const float* __restrict__ sb,
    const float* __restrict__ c_rb, const float* __restrict__ c_b1, const float* __restrict__ c_b2,
    const float* __restrict__ t_rb, const float* __restrict__ t_b1, const float* __restrict__ t_b2,
    const u16* __restrict__ ws, float* __restrict__ out, int NT)
{
  __shared__ __attribute__((aligned(16))) char Wp[2][PANEL_B];  // weight panel double-buffer (32 KB)

  const int tid = threadIdx.x, blk = blockIdx.x;
  const int lane = tid & 63;
  const int lr = lane & 15, lg = lane >> 4;
  const int w = tid >> 6;                    // wave 0..3, each owns 16 torsion rows
  const int row0 = blk * 64 + w * 16;
  const int grow = row0 + lr;                // this lane's torsion row (m = lr)
  const char* wsb = (const char*)ws;

  // ---- panel staging: wave w stages stripes w*4..w*4+3 (1 KB each), write-side swizzle ----
  uint4 stg[4];
  int sdst[4];
  #pragma unroll
  for (int i = 0; i < 4; ++i){
    int off = (w * 4 + i) * 1024 + lane * 16;        // linear byte in panel
    int row = off >> 9, kb = off & 511;
    sdst[i] = row * 512 + (kb ^ ((row & 7) << 4));
  }
  #define STG_LOAD(p_) { _Pragma("unroll") for (int i_ = 0; i_ < 4; ++i_) \
      stg[i_] = *(const uint4*)(wsb + (size_t)(p_) * PANEL_B + (w * 4 + i_) * 1024 + lane * 16); }
  #define STG_WRITE(bs_) { _Pragma("unroll") for (int i_ = 0; i_ < 4; ++i_) \
      *(uint4*)(Wp[bs_] + sdst[i_]) = stg[i_]; }
  // weight A-fragment: rows (ntb+lr) of panel, k = kt*32 + lg*8 + 0..7
  #define LDA(bs_, ntb_, kt_) (*(const short8*)(Wp[bs_] + ((ntb_) + lr) * 512 + \
      ((((kt_) * 64) + lg * 16) ^ ((lr & 7) << 4))))

  // ---- gather B-fragments: X_in[m=lr][k = kt*32+lg*8+j] direct from h16 ----
  int4 idx4 = {0, 0, 0, 0};
  if (grow < NT) idx4 = ((const int4*)idxs)[grow];
  #define GLOAD(dst_, kh_) { _Pragma("unroll") for (int kt_ = 0; kt_ < 8; ++kt_){ \
      const int node_ = (kh_) * 2 + (kt_ >> 2); \
      const int ni_ = (node_ == 0) ? idx4.x : (node_ == 1) ? idx4.y : (node_ == 2) ? idx4.z : idx4.w; \
      const int off_ = (kt_ * 32 + lg * 8) & 127; \
      if (H16) dst_[kt_] = *(const short8*)(h16 + (size_t)ni_ * 128 + off_); \
      else { const float* fp_ = h + (size_t)ni_ * 128 + off_; \
        float4 qa_ = *(const float4*)fp_, qb_ = *(const float4*)(fp_ + 4); \
        short8 v_; \
        v_[0]=(short)f2b(qa_.x); v_[1]=(short)f2b(qa_.y); v_[2]=(short)f2b(qa_.z); v_[3]=(short)f2b(qa_.w); \
        v_[4]=(short)f2b(qb_.x); v_[5]=(short)f2b(qb_.y); v_[6]=(short)f2b(qb_.z); v_[7]=(short)f2b(qb_.w); \
        dst_[kt_] = v_; } } }

  // ---- D-space words -> next-layer B-fragments (8 shfl + 4 select per k-step) ----
  // Zw[2T+q] on lane (lg,lr) = bf16 pair z[m=lr][n = T*16 + lg*4 + 2q (+1)]
  // F[kt] element j = z[m=lr][k = kt*32 + lg*8 + j]
  #define REPACK(Zw_, F_) { \
    const int s0_ = ((lg & 1) * 2) * 16 + lr; \
    const int s1_ = s0_ + 16; \
    const bool hi_ = (lg >> 1) != 0; \
    _Pragma("unroll") for (int kt_ = 0; kt_ < 8; ++kt_){ \
      u32 a0_ = (u32)__shfl((int)Zw_[4*kt_+0], s0_, 64); \
      u32 b0_ = (u32)__shfl((int)Zw_[4*kt_+2], s0_, 64); \
      u32 a1_ = (u32)__shfl((int)Zw_[4*kt_+1], s0_, 64); \
      u32 b1_ = (u32)__shfl((int)Zw_[4*kt_+3], s0_, 64); \
      u32 a2_ = (u32)__shfl((int)Zw_[4*kt_+0], s1_, 64); \
      u32 b2_ = (u32)__shfl((int)Zw_[4*kt_+2], s1_, 64); \
      u32 a3_ = (u32)__shfl((int)Zw_[4*kt_+1], s1_, 64); \
      u32 b3_ = (u32)__shfl((int)Zw_[4*kt_+3], s1_, 64); \
      u32x4 t_ = { hi_ ? b0_ : a0_, hi_ ? b1_ : a1_, hi_ ? b2_ : a2_, hi_ ? b3_ : a3_ }; \
      F_[kt_] = __builtin_bit_cast(short8, t_); \
    } }

  // phase scaffold: 1 barrier per panel; issue loads early, LDS-write late (T14)
  int p = 0;
  #define PHASE_BEGIN  if (p + 2 < NPANEL) STG_LOAD(p + 2);
  #define PHASE_END    __syncthreads(); if (p + 2 < NPANEL) STG_WRITE(p & 1); ++p;

  // ---- prologue: gather kh0 frags + stage panels 0,1 ----
  short8 Gf0[8], Gf1[8];
  GLOAD(Gf0, 0);
  STG_LOAD(0); STG_WRITE(0);
  STG_LOAD(1); STG_WRITE(1);
  __syncthreads();

  // ================ shared layer: x = elu(concat(h[idx]) @ sw.T + sb) ================
  f32x4 accS[16];
  #pragma unroll
  for (int T = 0; T < 16; ++T) accS[T] = (f32x4){0.f, 0.f, 0.f, 0.f};

  #pragma unroll
  for (int g = 0; g < 8; ++g){            // phases 0..7: k-half 0
    if (g == 6) GLOAD(Gf1, 1);            // prefetch k-half-1 gather frags
    PHASE_BEGIN;
    #pragma unroll
    for (int tl = 0; tl < 2; ++tl)
      #pragma unroll
      for (int kt = 0; kt < 8; ++kt){
        short8 a = LDA(p & 1, tl * 16, kt);
        accS[g * 2 + tl] = __builtin_amdgcn_mfma_f32_16x16x32_bf16(a, Gf0[kt], accS[g * 2 + tl], 0, 0, 0);
      }
    PHASE_END;
  }
  #pragma unroll
  for (int g = 0; g < 8; ++g){            // phases 8..15: k-half 1
    PHASE_BEGIN;
    #pragma unroll
    for (int tl = 0; tl < 2; ++tl)
      #pragma unroll
      for (int kt = 0; kt < 8; ++kt){
        short8 a = LDA(p & 1, tl * 16, kt);
        accS[g * 2 + tl] = __builtin_amdgcn_mfma_f32_16x16x32_bf16(a, Gf1[kt], accS[g * 2 + tl], 0, 0, 0);
      }
    PHASE_END;
  }

  // finalize x in D-space words (bf16-packed); n = T*16 + lg*4 + r
  u32 XD[32];
  #pragma unroll
  for (int T = 0; T < 16; ++T){
    const float* bp = sb + T * 16 + lg * 4;
    float e0 = elu1(accS[T][0] + bp[0]);
    float e1 = elu1(accS[T][1] + bp[1]);
    float e2 = elu1(accS[T][2] + bp[2]);
    float e3 = elu1(accS[T][3] + bp[3]);
    XD[2 * T]     = packbf(e0, e1);
    XD[2 * T + 1] = packbf(e2, e3);
  }

  // ================ heads: c (score) then t (coeffs), all in registers ================
  float scC[4], scT[4];
  #pragma unroll
  for (int hd = 0; hd < 2; ++hd){
    const float* RB = hd ? t_rb : c_rb;
    const float* B1 = hd ? t_b1 : c_b1;
    const float* B2 = hd ? t_b2 : c_b2;

    short8 Xf[8];
    REPACK(XD, Xf);
    u32 Zw[32];

    // y = x + elu(x @ rw.T + rb)
    #pragma unroll
    for (int g = 0; g < 8; ++g){
      PHASE_BEGIN;
      #pragma unroll
      for (int tl = 0; tl < 2; ++tl){
        f32x4 acc = (f32x4){0.f, 0.f, 0.f, 0.f};
        #pragma unroll
        for (int kt = 0; kt < 8; ++kt){
          short8 a = LDA(p & 1, tl * 16, kt);
          acc = __builtin_amdgcn_mfma_f32_16x16x32_bf16(a, Xf[kt], acc, 0, 0, 0);
        }
        const int T = g * 2 + tl;
        const float* bp = RB + g * 32 + tl * 16 + lg * 4;
        float x0 = b2f((u16)(XD[2*T] & 0xffff)),   x1 = b2f((u16)(XD[2*T] >> 16));
        float x2 = b2f((u16)(XD[2*T+1] & 0xffff)), x3 = b2f((u16)(XD[2*T+1] >> 16));
        float y0 = x0 + elu1(acc[0] + bp[0]);
        float y1 = x1 + elu1(acc[1] + bp[1]);
        float y2 = x2 + elu1(acc[2] + bp[2]);
        float y3 = x3 + elu1(acc[3] + bp[3]);
        Zw[2*T] = packbf(y0, y1); Zw[2*T+1] = packbf(y2, y3);
      }
      PHASE_END;
    }
    short8 Yf[8];
    REPACK(Zw, Yf);

    // v = elu(y @ w1.T + b1)
    #pragma unroll
    for (int g = 0; g < 8; ++g){
      PHASE_BEGIN;
      #pragma unroll
      for (int tl = 0; tl < 2; ++tl){
        f32x4 acc = (f32x4){0.f, 0.f, 0.f, 0.f};
        #pragma unroll
        for (int kt = 0; kt < 8; ++kt){
          short8 a = LDA(p & 1, tl * 16, kt);
          acc = __builtin_amdgcn_mfma_f32_16x16x32_bf16(a, Yf[kt], acc, 0, 0, 0);
        }
        const int T = g * 2 + tl;
        const float* bp = B1 + g * 32 + tl * 16 + lg * 4;
        Zw[2*T]   = packbf(elu1(acc[0] + bp[0]), elu1(acc[1] + bp[1]));
        Zw[2*T+1] = packbf(elu1(acc[2] + bp[2]), elu1(acc[3] + bp[3]));
      }
      PHASE_END;
    }
    short8 Vf[8];
    REPACK(Zw, Vf);

    // out16 = v @ w2p.T (padded [32][256]); single panel, tile 0 only
    PHASE_BEGIN;
    {
      f32x4 acc = (f32x4){0.f, 0.f, 0.f, 0.f};
      #pragma unroll
      for (int kt = 0; kt < 8; ++kt){
        short8 a = LDA(p & 1, 0, kt);
        acc = __builtin_amdgcn_mfma_f32_16x16x32_bf16(a, Vf[kt], acc, 0, 0, 0);
      }
      if (hd == 0){
        #pragma unroll
        for (int r = 0; r < 4; ++r){
          int nn = lg * 4 + r;
          scC[r] = acc[r] + ((nn < NPER) ? B2[nn] : 0.f);
        }
      } else {
        #pragma unroll
        for (int r = 0; r < 4; ++r){
          int nn = lg * 4 + r;
          scT[r] = acc[r] + ((nn < NPER) ? B2[nn] : 0.f);
        }
      }
    }
    PHASE_END;
  }

  // ---- epilogue: lanes lg<2 hold n = lg*4+r; m = lr ----
  if (grow < NT && lg < 2){
    #pragma unroll
    for (int r = 0; r < 4; ++r){
      int nn = lg * 4 + r;
      if (nn < NPER){
        float s = scC[r];
        float c = scT[r];
        out[(size_t)grow * 6 + nn] = s;
        out[(size_t)NT * 6 + (size_t)grow * 6 + nn] = c * 1e-3f * (1.f / (1.f + __expf(-s)));
      }
    }
  }
}

extern "C" void kernel_launch(void* const* d_in, const int* in_sizes, int n_in,
                              void* d_out, int out_size, void* d_ws, size_t ws_size,
                              hipStream_t stream){
  const float* h    = (const float*)d_in[0];
  const int*   idxs = (const int*)d_in[1];
  const float* sw   = (const float*)d_in[2];
  const float* sb   = (const float*)d_in[3];
  const float* trw  = (const float*)d_in[4];
  const float* trb  = (const float*)d_in[5];
  const float* tw1  = (const float*)d_in[6];
  const float* tb1  = (const float*)d_in[7];
  const float* tw2  = (const float*)d_in[8];
  const float* tb2  = (const float*)d_in[9];
  const float* crw  = (const float*)d_in[10];
  const float* crb  = (const float*)d_in[11];
  const float* cw1  = (const float*)d_in[12];
  const float* cb1  = (const float*)d_in[13];
  const float* cw2  = (const float*)d_in[14];
  const float* cb2  = (const float*)d_in[15];
  u16* ws    = (u16*)d_ws;
  float* out = (float*)d_out;
  const int NT = in_sizes[1] / 4;
  const int nh = in_sizes[0];                       // N_NODES * 128
  const bool useH16 = ws_size >= (size_t)(WS_WELE + nh) * 2;

  hipLaunchKernelGGL(convert_weights, dim3((WS_WELE + 255) / 256), dim3(256), 0, stream,
                     sw, crw, cw1, cw2, trw, tw1, tw2, ws);
  u16* h16 = ws + WS_WELE;
  const int nblk = (NT + 63) / 64;
  if (useH16){
    const int n8 = nh / 8;
    hipLaunchKernelGGL(convert_h, dim3((n8 + 255) / 256), dim3(256), 0, stream, h, h16, n8);
    torsion_kernel<true><<<dim3(nblk), dim3(256), 0, stream>>>(
        h, h16, idxs, sb, crb, cb1, cb2, trb, tb1, tb2, ws, out, NT);
  } else {
    torsion_kernel<false><<<dim3(nblk), dim3(256), 0, stream>>>(
        h, h16, idxs, sb, crb, cb1, cb2, trb, tb1, tb2, ws, out, NT);
  }
}

// Round 7
// 786.490 us; speedup vs baseline: 2.4282x; 2.4282x over previous
//
#include <hip/hip_runtime.h>
#include <stdint.h>

typedef __attribute__((ext_vector_type(8))) short short8;
typedef __attribute__((ext_vector_type(4))) float f32x4;
typedef __attribute__((ext_vector_type(2))) unsigned int u32x2;
typedef unsigned short u16;
typedef unsigned int u32;

#define NPER 6
#define NPANEL 50
#define WS_WELE (NPANEL * 8192)   // 50 pre-swizzled 16KB panels; h16 follows

__device__ inline u16 f2b(float f){                 // f32 -> bf16 (RNE)
  u32 u = __builtin_bit_cast(u32, f);
  u = u + 0x7FFFu + ((u >> 16) & 1u);
  return (u16)(u >> 16);
}
__device__ inline float b2f(u16 v){ return __builtin_bit_cast(float, ((u32)v) << 16); }
__device__ inline float elu1(float x){ return x > 0.f ? x : (__expf(x) - 1.f); }
__device__ inline u32 packbf(float a, float b){ return (u32)f2b(a) | ((u32)f2b(b) << 16); }

// ---- phase-ordered, PRE-SWIZZLED weight panels ----
// p 0..15: sw (k32 = p); 16..23: c_rw; 24..31: c_w1; 32: c_w2 pad[32][256]
// p 33..40: t_rw; 41..48: t_w1; 49: t_w2 pad
// k32 panel: [256 n][32 k] rows 64B, content[n][kk] = W[n][kk with granule ^ ((n>>1)&3)]
// w2 panel : [32 n][256 k] rows 512B, granule ^ (n&7)
__global__ __launch_bounds__(256) void convert_weights(
    const float* __restrict__ sw, const float* __restrict__ crw, const float* __restrict__ cw1,
    const float* __restrict__ cw2, const float* __restrict__ trw, const float* __restrict__ tw1,
    const float* __restrict__ tw2, u16* __restrict__ ws){
  int i = blockIdx.x * 256 + threadIdx.x;
  if (i >= WS_WELE) return;
  int p = i >> 13, e = i & 8191;
  float v;
  if (p == 32 || p == 49){
    int n = e >> 8, kc = e & 255;
    int ks = (kc & 7) | ((((kc >> 3) ^ (n & 7)) & 31) << 3);
    const float* w2 = (p == 32) ? cw2 : tw2;
    v = (n < NPER) ? w2[n * 256 + ks] : 0.f;
  } else {
    int n = e >> 5, kk = e & 31;
    int ks = (kk & 7) | ((((kk >> 3) ^ ((n >> 1) & 3)) & 3) << 3);
    if (p < 16){ v = sw[n * 512 + p * 32 + ks]; }
    else {
      const float* src; int kb;
      if (p < 24)      { src = crw; kb = (p - 16) * 32; }
      else if (p < 32) { src = cw1; kb = (p - 24) * 32; }
      else if (p < 41) { src = trw; kb = (p - 33) * 32; }
      else             { src = tw1; kb = (p - 41) * 32; }
      v = src[n * 256 + kb + ks];
    }
  }
  ws[i] = f2b(v);
}

__global__ __launch_bounds__(256) void convert_h(
    const float* __restrict__ h, u16* __restrict__ h16, int n8){
  int i = blockIdx.x * 256 + threadIdx.x;
  if (i >= n8) return;
  const float4* src = (const float4*)(h + (size_t)i * 8);
  float4 q0 = src[0], q1 = src[1];
  short8 v;
  v[0]=(short)f2b(q0.x); v[1]=(short)f2b(q0.y); v[2]=(short)f2b(q0.z); v[3]=(short)f2b(q0.w);
  v[4]=(short)f2b(q1.x); v[5]=(short)f2b(q1.y); v[6]=(short)f2b(q1.z); v[7]=(short)f2b(q1.w);
  *(short8*)(h16 + (size_t)i * 8) = v;
}

// ---- staging / fragment macros (expand inside kernel scope) ----
#define WLOAD(pn) { const u16* s_ = ws + (size_t)(pn) * 8192 + tid * 16; \
  wr0 = *(const short8*)s_; wr1 = *(const short8*)(s_ + 8); }
#define WSTORE(pn) { char* d_ = Wbuf[(pn) & 1] + tid * 32; \
  *(short8*)d_ = wr0; *(short8*)(d_ + 16) = wr1; }

#define LOADC(c) { const int c_ = (c); \
  int nd_ = ((c_>>1)==0)?idx4.x:((c_>>1)==1)?idx4.y:((c_>>1)==2)?idx4.z:idx4.w; \
  const size_t o_ = (size_t)nd_ * 128 + (c_ & 1) * 64 + sq * 16; \
  if (H16){ rgA = *(const short8*)(h16 + o_); rgB = *(const short8*)(h16 + o_ + 8); } \
  else { float4 qa_=*(const float4*)(h+o_), qb_=*(const float4*)(h+o_+4); \
         float4 qc_=*(const float4*)(h+o_+8), qd_=*(const float4*)(h+o_+12); \
    rgA[0]=(short)f2b(qa_.x); rgA[1]=(short)f2b(qa_.y); rgA[2]=(short)f2b(qa_.z); rgA[3]=(short)f2b(qa_.w); \
    rgA[4]=(short)f2b(qb_.x); rgA[5]=(short)f2b(qb_.y); rgA[6]=(short)f2b(qb_.z); rgA[7]=(short)f2b(qb_.w); \
    rgB[0]=(short)f2b(qc_.x); rgB[1]=(short)f2b(qc_.y); rgB[2]=(short)f2b(qc_.z); rgB[3]=(short)f2b(qc_.w); \
    rgB[4]=(short)f2b(qd_.x); rgB[5]=(short)f2b(qd_.y); rgB[6]=(short)f2b(qd_.z); rgB[7]=(short)f2b(qd_.w); } }
#define STOREC(c) { char* b_ = Zb + (((c) & 1) << 14) + srow * 128; const int sw_ = (srow & 7) << 4; \
  *(short8*)(b_ + ((sq * 32) ^ sw_))      = rgA; \
  *(short8*)(b_ + ((sq * 32 + 16) ^ sw_)) = rgB; }

// 16 MFMA per call: acc[wf][af] += Wpanel[wn*64+wf*16+..][k32] * act[wm*64+af*16+..][k32]
#define GEMM32(bf_, AB_, RS_, kb_) { \
  const char* wb_ = Wbuf[bf_]; \
  short8 wf0_, wf1_, wf2_, wf3_, a_; \
  { int n_ = wn*64 + lr;      wf0_ = *(const short8*)(wb_ + n_*64 + ((lg*16) ^ (((n_>>1)&3)<<4))); } \
  { int n_ = wn*64 + 16 + lr; wf1_ = *(const short8*)(wb_ + n_*64 + ((lg*16) ^ (((n_>>1)&3)<<4))); } \
  { int n_ = wn*64 + 32 + lr; wf2_ = *(const short8*)(wb_ + n_*64 + ((lg*16) ^ (((n_>>1)&3)<<4))); } \
  { int n_ = wn*64 + 48 + lr; wf3_ = *(const short8*)(wb_ + n_*64 + ((lg*16) ^ (((n_>>1)&3)<<4))); } \
  _Pragma("unroll") for (int af_ = 0; af_ < 4; ++af_){ \
    int r_ = wm*64 + af_*16 + lr; \
    a_ = *(const short8*)((AB_) + r_*(RS_) + (((kb_) + lg*16) ^ ((r_&7)<<4))); \
    acc[0][af_] = __builtin_amdgcn_mfma_f32_16x16x32_bf16(wf0_, a_, acc[0][af_], 0, 0, 0); \
    acc[1][af_] = __builtin_amdgcn_mfma_f32_16x16x32_bf16(wf1_, a_, acc[1][af_], 0, 0, 0); \
    acc[2][af_] = __builtin_amdgcn_mfma_f32_16x16x32_bf16(wf2_, a_, acc[2][af_], 0, 0, 0); \
    acc[3][af_] = __builtin_amdgcn_mfma_f32_16x16x32_bf16(wf3_, a_, acc[3][af_], 0, 0, 0); } }

#define ZERO_ACC() { _Pragma("unroll") for (int i_ = 0; i_ < 4; ++i_) \
  _Pragma("unroll") for (int j_ = 0; j_ < 4; ++j_) acc[i_][j_] = (f32x4){0.f,0.f,0.f,0.f}; }

template<bool H16>
__global__ __launch_bounds__(512) void torsion_kernel(
    const float* __restrict__ h, const u16* __restrict__ h16,
    const int* __restrict__ idxs, const float* __restrict__ sb,
    const float* __restrict__ c_rb, const float* __restrict__ c_b1, const float* __restrict__ c_b2,
    const float* __restrict__ t_rb, const float* __restrict__ t_b1, const float* __restrict__ t_b2,
    const u16* __restrict__ ws, float* __restrict__ out, int NT)
{
  __shared__ __attribute__((aligned(16))) char Xb[65536];      // [128][256] bf16 swizzled
  __shared__ __attribute__((aligned(16))) char Zb[65536];      // gather 2x16KB, then Y/V
  __shared__ __attribute__((aligned(16))) char Wbuf[2][16384]; // weight panel dbuf

  const int tid = threadIdx.x, blk = blockIdx.x;
  const int lane = tid & 63, lr = lane & 15, lg = lane >> 4;
  const int wv = tid >> 6, wm = wv & 1, wn = wv >> 1;

  const int srow = tid >> 2, sq = tid & 3;       // gather staging: row, granule pair
  const int sgrow = blk * 128 + srow;
  int4 idx4 = (sgrow < NT) ? ((const int4*)idxs)[sgrow] : (int4){0, 0, 0, 0};
  short8 rgA, rgB;     // gather staging regs
  short8 wr0, wr1;     // weight staging regs

  f32x4 acc[4][4];
  ZERO_ACC();

  // ---- prologue: panel 0 + gather chunk 0 ----
  WLOAD(0); WSTORE(0);
  LOADC(0); STOREC(0);
  __syncthreads();

  // ================ stage A: x = elu(concat(h[idx]) @ sw.T + sb), phases 0..15 ================
  #pragma unroll 2
  for (int p = 0; p < 16; ++p){
    WLOAD(p + 1);
    if (((p & 1) == 0) && p < 14) LOADC((p >> 1) + 1);
    const char* cb = Zb + (((p >> 1) & 1) << 14);
    GEMM32(p & 1, cb, 128, (p & 1) * 64);
    if (p == 15){
      #pragma unroll
      for (int wf = 0; wf < 4; ++wf){
        const int col0 = wn * 64 + wf * 16 + lg * 4;
        const float4 bb = *(const float4*)(sb + col0);
        #pragma unroll
        for (int af = 0; af < 4; ++af){
          const int row = wm * 64 + af * 16 + lr;
          u32x2 pk = { packbf(elu1(acc[wf][af][0] + bb.x), elu1(acc[wf][af][1] + bb.y)),
                       packbf(elu1(acc[wf][af][2] + bb.z), elu1(acc[wf][af][3] + bb.w)) };
          *(u32x2*)(Xb + row * 512 + ((col0 * 2) ^ ((row & 7) << 4))) = pk;
        }
      }
    }
    if (((p & 1) == 1) && p < 15) STOREC((p >> 1) + 1);
    WSTORE(p + 1);
    __syncthreads();
  }

  // ================ heads: c (score, phases 16..32) then t (coeffs, 33..49) ================
  f32x4 scC = (f32x4){0,0,0,0}, scT = (f32x4){0,0,0,0};
  #pragma unroll
  for (int hd = 0; hd < 2; ++hd){
    const int pb = 16 + hd * 17;
    const float* RB = hd ? t_rb : c_rb;
    const float* B1 = hd ? t_b1 : c_b1;
    const float* B2 = hd ? t_b2 : c_b2;

    // y = x + elu(x @ rw.T + rb)    (phases pb..pb+7, reads Xb, writes Zb)
    ZERO_ACC();
    #pragma unroll 2
    for (int kk = 0; kk < 8; ++kk){
      const int p = pb + kk;
      WLOAD(p + 1);
      GEMM32(p & 1, Xb, 512, kk * 64);
      if (kk == 7){
        #pragma unroll
        for (int wf = 0; wf < 4; ++wf){
          const int col0 = wn * 64 + wf * 16 + lg * 4;
          const float4 bb = *(const float4*)(RB + col0);
          #pragma unroll
          for (int af = 0; af < 4; ++af){
            const int row = wm * 64 + af * 16 + lr;
            const int boff = (col0 * 2) ^ ((row & 7) << 4);
            u32x2 xv = *(const u32x2*)(Xb + row * 512 + boff);
            float y0 = b2f((u16)(xv[0] & 0xffff)) + elu1(acc[wf][af][0] + bb.x);
            float y1 = b2f((u16)(xv[0] >> 16))    + elu1(acc[wf][af][1] + bb.y);
            float y2 = b2f((u16)(xv[1] & 0xffff)) + elu1(acc[wf][af][2] + bb.z);
            float y3 = b2f((u16)(xv[1] >> 16))    + elu1(acc[wf][af][3] + bb.w);
            u32x2 pk = { packbf(y0, y1), packbf(y2, y3) };
            *(u32x2*)(Zb + row * 512 + boff) = pk;
          }
        }
      }
      WSTORE(p + 1);
      __syncthreads();
    }

    // v = elu(y @ w1.T + b1)   (phases pb+8..pb+15, reads Zb, then overwrites Zb)
    ZERO_ACC();
    #pragma unroll 2
    for (int kk = 0; kk < 8; ++kk){
      const int p = pb + 8 + kk;
      WLOAD(p + 1);
      GEMM32(p & 1, Zb, 512, kk * 64);
      WSTORE(p + 1);
      if (kk == 7){
        __syncthreads();               // all Y reads complete before V overwrites Zb
        #pragma unroll
        for (int wf = 0; wf < 4; ++wf){
          const int col0 = wn * 64 + wf * 16 + lg * 4;
          const float4 bb = *(const float4*)(B1 + col0);
          #pragma unroll
          for (int af = 0; af < 4; ++af){
            const int row = wm * 64 + af * 16 + lr;
            u32x2 pk = { packbf(elu1(acc[wf][af][0] + bb.x), elu1(acc[wf][af][1] + bb.y)),
                         packbf(elu1(acc[wf][af][2] + bb.z), elu1(acc[wf][af][3] + bb.w)) };
            *(u32x2*)(Zb + row * 512 + ((col0 * 2) ^ ((row & 7) << 4))) = pk;
          }
        }
      }
      __syncthreads();
    }

    // out16 = v @ w2p.T   (phase pb+16; wave wv owns rows wv*16..+15)
    {
      const int p2 = pb + 16;
      if (p2 < NPANEL - 1) WLOAD(p2 + 1);
      f32x4 a1 = (f32x4){0, 0, 0, 0};
      const int vr = wv * 16 + lr;
      #pragma unroll
      for (int kt = 0; kt < 8; ++kt){
        short8 aw = *(const short8*)(Wbuf[p2 & 1] + lr * 512 + ((kt * 64 + lg * 16) ^ ((lr & 7) << 4)));
        short8 bv = *(const short8*)(Zb + vr * 512 + ((kt * 64 + lg * 16) ^ ((vr & 7) << 4)));
        a1 = __builtin_amdgcn_mfma_f32_16x16x32_bf16(aw, bv, a1, 0, 0, 0);
      }
      #pragma unroll
      for (int r = 0; r < 4; ++r){
        const int nn = lg * 4 + r;
        a1[r] += (nn < NPER) ? B2[nn] : 0.f;
      }
      if (hd == 0) scC = a1; else scT = a1;
      if (p2 < NPANEL - 1) WSTORE(p2 + 1);
      __syncthreads();
    }
  }

  // ---- epilogue: score & coeff for row (wv*16+lr) both live in this lane ----
  const int grow = blk * 128 + wv * 16 + lr;
  if (grow < NT){
    #pragma unroll
    for (int r = 0; r < 4; ++r){
      const int nn = lg * 4 + r;
      if (nn < NPER){
        const float s = scC[r], c = scT[r];
        out[(size_t)grow * 6 + nn] = s;
        out[(size_t)NT * 6 + (size_t)grow * 6 + nn] = c * 1e-3f * (1.f / (1.f + __expf(-s)));
      }
    }
  }
}

extern "C" void kernel_launch(void* const* d_in, const int* in_sizes, int n_in,
                              void* d_out, int out_size, void* d_ws, size_t ws_size,
                              hipStream_t stream){
  const float* h    = (const float*)d_in[0];
  const int*   idxs = (const int*)d_in[1];
  const float* sw   = (const float*)d_in[2];
  const float* sb   = (const float*)d_in[3];
  const float* trw  = (const float*)d_in[4];
  const float* trb  = (const float*)d_in[5];
  const float* tw1  = (const float*)d_in[6];
  const float* tb1  = (const float*)d_in[7];
  const float* tw2  = (const float*)d_in[8];
  const float* tb2  = (const float*)d_in[9];
  const float* crw  = (const float*)d_in[10];
  const float* crb  = (const float*)d_in[11];
  const float* cw1  = (const float*)d_in[12];
  const float* cb1  = (const float*)d_in[13];
  const float* cw2  = (const float*)d_in[14];
  const float* cb2  = (const float*)d_in[15];
  u16* ws    = (u16*)d_ws;
  float* out = (float*)d_out;
  const int NT = in_sizes[1] / 4;
  const int nh = in_sizes[0];
  const bool useH16 = ws_size >= (size_t)(WS_WELE + nh) * 2;

  hipLaunchKernelGGL(convert_weights, dim3((WS_WELE + 255) / 256), dim3(256), 0, stream,
                     sw, crw, cw1, cw2, trw, tw1, tw2, ws);
  u16* h16 = ws + WS_WELE;
  const int nblk = (NT + 127) / 128;
  if (useH16){
    const int n8 = nh / 8;
    hipLaunchKernelGGL(convert_h, dim3((n8 + 255) / 256), dim3(256), 0, stream, h, h16, n8);
    torsion_kernel<true><<<dim3(nblk), dim3(512), 0, stream>>>(
        h, h16, idxs, sb, crb, cb1, cb2, trb, tb1, tb2, ws, out, NT);
  } else {
    torsion_kernel<false><<<dim3(nblk), dim3(512), 0, stream>>>(
        h, h16, idxs, sb, crb, cb1, cb2, trb, tb1, tb2, ws, out, NT);
  }
}

// Round 8
// 624.840 us; speedup vs baseline: 3.0564x; 1.2587x over previous
//
#include <hip/hip_runtime.h>
#include <stdint.h>

typedef __attribute__((ext_vector_type(8))) short short8;
typedef __attribute__((ext_vector_type(4))) float f32x4;
typedef __attribute__((ext_vector_type(2))) unsigned int u32x2;
typedef unsigned short u16;
typedef unsigned int u32;

#define NPER 6
#define NPANEL 50
#define WS_WELE (NPANEL * 8192)   // 50 pre-swizzled 16KB panels; h16 follows

__device__ inline u16 f2b(float f){                 // f32 -> bf16 (RNE)
  u32 u = __builtin_bit_cast(u32, f);
  u = u + 0x7FFFu + ((u >> 16) & 1u);
  return (u16)(u >> 16);
}
__device__ inline float b2f(u16 v){ return __builtin_bit_cast(float, ((u32)v) << 16); }
__device__ inline float elu1(float x){ return x > 0.f ? x : (__expf(x) - 1.f); }
__device__ inline u32 packbf(float a, float b){ return (u32)f2b(a) | ((u32)f2b(b) << 16); }

// ---- phase-ordered, PRE-SWIZZLED weight panels (identical to R7) ----
__global__ __launch_bounds__(256) void convert_weights(
    const float* __restrict__ sw, const float* __restrict__ crw, const float* __restrict__ cw1,
    const float* __restrict__ cw2, const float* __restrict__ trw, const float* __restrict__ tw1,
    const float* __restrict__ tw2, u16* __restrict__ ws){
  int i = blockIdx.x * 256 + threadIdx.x;
  if (i >= WS_WELE) return;
  int p = i >> 13, e = i & 8191;
  float v;
  if (p == 32 || p == 49){
    int n = e >> 8, kc = e & 255;
    int ks = (kc & 7) | ((((kc >> 3) ^ (n & 7)) & 31) << 3);
    const float* w2 = (p == 32) ? cw2 : tw2;
    v = (n < NPER) ? w2[n * 256 + ks] : 0.f;
  } else {
    int n = e >> 5, kk = e & 31;
    int ks = (kk & 7) | ((((kk >> 3) ^ ((n >> 1) & 3)) & 3) << 3);
    if (p < 16){ v = sw[n * 512 + p * 32 + ks]; }
    else {
      const float* src; int kb;
      if (p < 24)      { src = crw; kb = (p - 16) * 32; }
      else if (p < 32) { src = cw1; kb = (p - 24) * 32; }
      else if (p < 41) { src = trw; kb = (p - 33) * 32; }
      else             { src = tw1; kb = (p - 41) * 32; }
      v = src[n * 256 + kb + ks];
    }
  }
  ws[i] = f2b(v);
}

__global__ __launch_bounds__(256) void convert_h(
    const float* __restrict__ h, u16* __restrict__ h16, int n8){
  int i = blockIdx.x * 256 + threadIdx.x;
  if (i >= n8) return;
  const float4* src = (const float4*)(h + (size_t)i * 8);
  float4 q0 = src[0], q1 = src[1];
  short8 v;
  v[0]=(short)f2b(q0.x); v[1]=(short)f2b(q0.y); v[2]=(short)f2b(q0.z); v[3]=(short)f2b(q0.w);
  v[4]=(short)f2b(q1.x); v[5]=(short)f2b(q1.y); v[6]=(short)f2b(q1.z); v[7]=(short)f2b(q1.w);
  *(short8*)(h16 + (size_t)i * 8) = v;
}

// ---- staging macros: two reg sets (E=even panels, O=odd), 16B-stride conflict-free ----
#define WLOAD_E(pn) { const u16* s_ = ws + (size_t)(pn) * 8192 + tid * 8; \
  wE0 = *(const short8*)s_; wE1 = *(const short8*)(s_ + 4096); }
#define WLOAD_O(pn) { const u16* s_ = ws + (size_t)(pn) * 8192 + tid * 8; \
  wO0 = *(const short8*)s_; wO1 = *(const short8*)(s_ + 4096); }
#define WSTORE_E(pn) { char* d_ = Wbuf[(pn) & 1] + tid * 16; \
  *(short8*)d_ = wE0; *(short8*)(d_ + 8192) = wE1; }
#define WSTORE_O(pn) { char* d_ = Wbuf[(pn) & 1] + tid * 16; \
  *(short8*)d_ = wO0; *(short8*)(d_ + 8192) = wO1; }
// phase p (literal): store panel p+1 (loaded at p-1), issue load of p+2
#define WSTAGE(p) { \
  if ((p) + 1 < NPANEL){ if ((((p) + 1) & 1)) { WSTORE_O((p) + 1); } else { WSTORE_E((p) + 1); } } \
  if ((p) + 2 < NPANEL){ if ((((p) + 2) & 1)) { WLOAD_O((p) + 2); } else { WLOAD_E((p) + 2); } } }

#define LOADC(c) { const int c_ = (c); \
  int nd_ = ((c_>>1)==0)?idx4.x:((c_>>1)==1)?idx4.y:((c_>>1)==2)?idx4.z:idx4.w; \
  const size_t o_ = (size_t)nd_ * 128 + (c_ & 1) * 64 + sq * 16; \
  if (H16){ rgA = *(const short8*)(h16 + o_); rgB = *(const short8*)(h16 + o_ + 8); } \
  else { float4 qa_=*(const float4*)(h+o_), qb_=*(const float4*)(h+o_+4); \
         float4 qc_=*(const float4*)(h+o_+8), qd_=*(const float4*)(h+o_+12); \
    rgA[0]=(short)f2b(qa_.x); rgA[1]=(short)f2b(qa_.y); rgA[2]=(short)f2b(qa_.z); rgA[3]=(short)f2b(qa_.w); \
    rgA[4]=(short)f2b(qb_.x); rgA[5]=(short)f2b(qb_.y); rgA[6]=(short)f2b(qb_.z); rgA[7]=(short)f2b(qb_.w); \
    rgB[0]=(short)f2b(qc_.x); rgB[1]=(short)f2b(qc_.y); rgB[2]=(short)f2b(qc_.z); rgB[3]=(short)f2b(qc_.w); \
    rgB[4]=(short)f2b(qd_.x); rgB[5]=(short)f2b(qd_.y); rgB[6]=(short)f2b(qd_.z); rgB[7]=(short)f2b(qd_.w); } }
#define STOREC(c) { char* b_ = Zb + (((c) & 1) << 14) + srow * 128; const int sw_ = (srow & 7) << 4; \
  *(short8*)(b_ + ((sq * 32) ^ sw_))      = rgA; \
  *(short8*)(b_ + ((sq * 32 + 16) ^ sw_)) = rgB; }

// 16 MFMA: acc[wf][af] += Wpanel[wn*64+wf*16+..][k32] * act[wm*64+af*16+..][k32]
#define GEMM32(bf_, AB_, RS_, kb_) { \
  const char* wb_ = Wbuf[bf_]; \
  short8 wf0_, wf1_, wf2_, wf3_, a_; \
  { int n_ = wn*64 + lr;      wf0_ = *(const short8*)(wb_ + n_*64 + ((lg*16) ^ (((n_>>1)&3)<<4))); } \
  { int n_ = wn*64 + 16 + lr; wf1_ = *(const short8*)(wb_ + n_*64 + ((lg*16) ^ (((n_>>1)&3)<<4))); } \
  { int n_ = wn*64 + 32 + lr; wf2_ = *(const short8*)(wb_ + n_*64 + ((lg*16) ^ (((n_>>1)&3)<<4))); } \
  { int n_ = wn*64 + 48 + lr; wf3_ = *(const short8*)(wb_ + n_*64 + ((lg*16) ^ (((n_>>1)&3)<<4))); } \
  __builtin_amdgcn_s_setprio(1); \
  _Pragma("unroll") for (int af_ = 0; af_ < 4; ++af_){ \
    int r_ = wm*64 + af_*16 + lr; \
    a_ = *(const short8*)((AB_) + r_*(RS_) + (((kb_) + lg*16) ^ ((r_&7)<<4))); \
    acc[0][af_] = __builtin_amdgcn_mfma_f32_16x16x32_bf16(wf0_, a_, acc[0][af_], 0, 0, 0); \
    acc[1][af_] = __builtin_amdgcn_mfma_f32_16x16x32_bf16(wf1_, a_, acc[1][af_], 0, 0, 0); \
    acc[2][af_] = __builtin_amdgcn_mfma_f32_16x16x32_bf16(wf2_, a_, acc[2][af_], 0, 0, 0); \
    acc[3][af_] = __builtin_amdgcn_mfma_f32_16x16x32_bf16(wf3_, a_, acc[3][af_], 0, 0, 0); } \
  __builtin_amdgcn_s_setprio(0); }

#define ZERO_ACC() { _Pragma("unroll") for (int i_ = 0; i_ < 4; ++i_) \
  _Pragma("unroll") for (int j_ = 0; j_ < 4; ++j_) acc[i_][j_] = (f32x4){0.f,0.f,0.f,0.f}; }

// raw barrier: drain LDS writes, keep global loads in flight (T4)
#define BAR() { asm volatile("s_waitcnt lgkmcnt(0)" ::: "memory"); \
  __builtin_amdgcn_sched_barrier(0); \
  __builtin_amdgcn_s_barrier(); \
  __builtin_amdgcn_sched_barrier(0); }

template<bool H16>
__global__ __launch_bounds__(512) void torsion_kernel(
    const float* __restrict__ h, const u16* __restrict__ h16,
    const int* __restrict__ idxs, const float* __restrict__ sb,
    const float* __restrict__ c_rb, const float* __restrict__ c_b1, const float* __restrict__ c_b2,
    const float* __restrict__ t_rb, const float* __restrict__ t_b1, const float* __restrict__ t_b2,
    const u16* __restrict__ ws, float* __restrict__ out, int NT)
{
  __shared__ __attribute__((aligned(16))) char Xb[65536];      // [128][256] bf16 swizzled
  __shared__ __attribute__((aligned(16))) char Zb[65536];      // gather 2x16KB, then Y/V
  __shared__ __attribute__((aligned(16))) char Wbuf[2][16384]; // weight panel dbuf

  const int tid = threadIdx.x, blk = blockIdx.x;
  const int lane = tid & 63, lr = lane & 15, lg = lane >> 4;
  const int wv = tid >> 6, wm = wv & 1, wn = wv >> 1;

  const int srow = tid >> 2, sq = tid & 3;
  const int sgrow = blk * 128 + srow;
  int4 idx4 = (sgrow < NT) ? ((const int4*)idxs)[sgrow] : (int4){0, 0, 0, 0};
  short8 rgA, rgB;                 // gather staging regs
  short8 wE0, wE1, wO0, wO1;       // panel staging regs (even/odd sets)

  f32x4 acc[4][4];
  ZERO_ACC();

  // ---- prologue: panel 0 staged, panel 1 in regs, gather chunk 0 staged ----
  WLOAD_E(0); WSTORE_E(0);
  WLOAD_O(1);
  LOADC(0); STOREC(0);
  BAR();

  // ================ stage A: x = elu(concat(h[idx]) @ sw.T + sb), phases 0..15 ================
  #pragma unroll
  for (int p = 0; p < 16; ++p){
    if ((p & 1) == 1 && p < 15) STOREC((p >> 1) + 1);   // chunk staged 1.5 phases after issue
    WSTAGE(p);
    if ((p & 1) == 0 && p < 14) LOADC((p >> 1) + 1);
    const char* cb = Zb + (((p >> 1) & 1) << 14);
    GEMM32(p & 1, cb, 128, (p & 1) * 64);
    if (p == 15){
      #pragma unroll
      for (int wf = 0; wf < 4; ++wf){
        const int col0 = wn * 64 + wf * 16 + lg * 4;
        const float4 bb = *(const float4*)(sb + col0);
        #pragma unroll
        for (int af = 0; af < 4; ++af){
          const int row = wm * 64 + af * 16 + lr;
          u32x2 pk = { packbf(elu1(acc[wf][af][0] + bb.x), elu1(acc[wf][af][1] + bb.y)),
                       packbf(elu1(acc[wf][af][2] + bb.z), elu1(acc[wf][af][3] + bb.w)) };
          *(u32x2*)(Xb + row * 512 + ((col0 * 2) ^ ((row & 7) << 4))) = pk;
        }
      }
    }
    BAR();
  }

  // ================ heads: c (score, phases 16..32) then t (coeffs, 33..49) ================
  f32x4 scC = (f32x4){0,0,0,0}, scT = (f32x4){0,0,0,0};
  #pragma unroll
  for (int hd = 0; hd < 2; ++hd){
    const int pb = 16 + hd * 17;
    const float* RB = hd ? t_rb : c_rb;
    const float* B1 = hd ? t_b1 : c_b1;
    const float* B2 = hd ? t_b2 : c_b2;

    // y = x + elu(x @ rw.T + rb)   (reads Xb; kk==7 epilogue writes Zb)
    ZERO_ACC();
    #pragma unroll
    for (int kk = 0; kk < 8; ++kk){
      const int p = pb + kk;
      WSTAGE(p);
      GEMM32(p & 1, Xb, 512, kk * 64);
      if (kk == 7){
        #pragma unroll
        for (int wf = 0; wf < 4; ++wf){
          const int col0 = wn * 64 + wf * 16 + lg * 4;
          const float4 bb = *(const float4*)(RB + col0);
          #pragma unroll
          for (int af = 0; af < 4; ++af){
            const int row = wm * 64 + af * 16 + lr;
            const int boff = (col0 * 2) ^ ((row & 7) << 4);
            u32x2 xv = *(const u32x2*)(Xb + row * 512 + boff);
            float y0 = b2f((u16)(xv[0] & 0xffff)) + elu1(acc[wf][af][0] + bb.x);
            float y1 = b2f((u16)(xv[0] >> 16))    + elu1(acc[wf][af][1] + bb.y);
            float y2 = b2f((u16)(xv[1] & 0xffff)) + elu1(acc[wf][af][2] + bb.z);
            float y3 = b2f((u16)(xv[1] >> 16))    + elu1(acc[wf][af][3] + bb.w);
            u32x2 pk = { packbf(y0, y1), packbf(y2, y3) };
            *(u32x2*)(Zb + row * 512 + boff) = pk;
          }
        }
      }
      BAR();
    }

    // v = elu(y @ w1.T + b1)   (reads Zb(Y); kk==7: drain reads, then overwrite Zb with V)
    ZERO_ACC();
    #pragma unroll
    for (int kk = 0; kk < 8; ++kk){
      const int p = pb + 8 + kk;
      WSTAGE(p);
      GEMM32(p & 1, Zb, 512, kk * 64);
      if (kk == 7){
        BAR();                        // all Y reads complete before V overwrites Zb
        #pragma unroll
        for (int wf = 0; wf < 4; ++wf){
          const int col0 = wn * 64 + wf * 16 + lg * 4;
          const float4 bb = *(const float4*)(B1 + col0);
          #pragma unroll
          for (int af = 0; af < 4; ++af){
            const int row = wm * 64 + af * 16 + lr;
            u32x2 pk = { packbf(elu1(acc[wf][af][0] + bb.x), elu1(acc[wf][af][1] + bb.y)),
                         packbf(elu1(acc[wf][af][2] + bb.z), elu1(acc[wf][af][3] + bb.w)) };
            *(u32x2*)(Zb + row * 512 + ((col0 * 2) ^ ((row & 7) << 4))) = pk;
          }
        }
      }
      BAR();
    }

    // out16 = v @ w2p.T   (wave wv owns rows wv*16..+15)
    {
      const int p2 = pb + 16;
      WSTAGE(p2);
      f32x4 a1 = (f32x4){0, 0, 0, 0};
      const int vr = wv * 16 + lr;
      __builtin_amdgcn_s_setprio(1);
      #pragma unroll
      for (int kt = 0; kt < 8; ++kt){
        short8 aw = *(const short8*)(Wbuf[p2 & 1] + lr * 512 + ((kt * 64 + lg * 16) ^ ((lr & 7) << 4)));
        short8 bv = *(const short8*)(Zb + vr * 512 + ((kt * 64 + lg * 16) ^ ((vr & 7) << 4)));
        a1 = __builtin_amdgcn_mfma_f32_16x16x32_bf16(aw, bv, a1, 0, 0, 0);
      }
      __builtin_amdgcn_s_setprio(0);
      #pragma unroll
      for (int r = 0; r < 4; ++r){
        const int nn = lg * 4 + r;
        a1[r] += (nn < NPER) ? B2[nn] : 0.f;
      }
      if (hd == 0) scC = a1; else scT = a1;
      BAR();
    }
  }

  // ---- epilogue: score & coeff for row (wv*16+lr) both live in this lane ----
  const int grow = blk * 128 + wv * 16 + lr;
  if (grow < NT){
    #pragma unroll
    for (int r = 0; r < 4; ++r){
      const int nn = lg * 4 + r;
      if (nn < NPER){
        const float s = scC[r], c = scT[r];
        out[(size_t)grow * 6 + nn] = s;
        out[(size_t)NT * 6 + (size_t)grow * 6 + nn] = c * 1e-3f * (1.f / (1.f + __expf(-s)));
      }
    }
  }
}

extern "C" void kernel_launch(void* const* d_in, const int* in_sizes, int n_in,
                              void* d_out, int out_size, void* d_ws, size_t ws_size,
                              hipStream_t stream){
  const float* h    = (const float*)d_in[0];
  const int*   idxs = (const int*)d_in[1];
  const float* sw   = (const float*)d_in[2];
  const float* sb   = (const float*)d_in[3];
  const float* trw  = (const float*)d_in[4];
  const float* trb  = (const float*)d_in[5];
  const float* tw1  = (const float*)d_in[6];
  const float* tb1  = (const float*)d_in[7];
  const float* tw2  = (const float*)d_in[8];
  const float* tb2  = (const float*)d_in[9];
  const float* crw  = (const float*)d_in[10];
  const float* crb  = (const float*)d_in[11];
  const float* cw1  = (const float*)d_in[12];
  const float* cb1  = (const float*)d_in[13];
  const float* cw2  = (const float*)d_in[14];
  const float* cb2  = (const float*)d_in[15];
  u16* ws    = (u16*)d_ws;
  float* out = (float*)d_out;
  const int NT = in_sizes[1] / 4;
  const int nh = in_sizes[0];
  const bool useH16 = ws_size >= (size_t)(WS_WELE + nh) * 2;

  hipLaunchKernelGGL(convert_weights, dim3((WS_WELE + 255) / 256), dim3(256), 0, stream,
                     sw, crw, cw1, cw2, trw, tw1, tw2, ws);
  u16* h16 = ws + WS_WELE;
  const int nblk = (NT + 127) / 128;
  if (useH16){
    const int n8 = nh / 8;
    hipLaunchKernelGGL(convert_h, dim3((n8 + 255) / 256), dim3(256), 0, stream, h, h16, n8);
    torsion_kernel<true><<<dim3(nblk), dim3(512), 0, stream>>>(
        h, h16, idxs, sb, crb, cb1, cb2, trb, tb1, tb2, ws, out, NT);
  } else {
    torsion_kernel<false><<<dim3(nblk), dim3(512), 0, stream>>>(
        h, h16, idxs, sb, crb, cb1, cb2, trb, tb1, tb2, ws, out, NT);
  }
}